// Round 1
// baseline (38.222 us; speedup 1.0000x reference)
//
#include <hip/hip_runtime.h>
#include <stdint.h>

#define NB 256       // batch
#define NK 512       // in_features
#define NO 128       // out_features
#define NKD 16       // kernel_dims
#define NC 2048      // NO*NKD
#define OUTW 640     // NK + NO

typedef __attribute__((ext_vector_type(8))) short bf16x8;   // 8 bf16 bit patterns (4 VGPRs)
typedef __attribute__((ext_vector_type(4))) float f32x4;
typedef __attribute__((ext_vector_type(8))) unsigned short u16x8;
typedef __attribute__((ext_vector_type(4))) unsigned short u16x4;

__device__ __forceinline__ unsigned short f2bf(float f) {
  uint32_t u = __builtin_bit_cast(uint32_t, f);
  u += 0x7fffu + ((u >> 16) & 1u);          // RTNE (inputs are finite normals)
  return (unsigned short)(u >> 16);
}

// ---------------------------------------------------------------------------
// Kernel 1: x -> bf16 (Xb[256][512]); T[512][2048] -> transposed bf16 Wt[2048][512]
// ---------------------------------------------------------------------------
__global__ __launch_bounds__(256) void k_prep(const float* __restrict__ x,
                                              const float* __restrict__ T,
                                              unsigned short* __restrict__ Xb,
                                              unsigned short* __restrict__ Wt) {
  __shared__ unsigned short tile[64][66];   // +2 pad breaks bank collisions
  const int tid = threadIdx.x, bid = blockIdx.x;

  // x convert: 32768 float4 total = 256 blocks * 128
  if (tid < 128) {
    int idx = bid * 128 + tid;
    f32x4 v = ((const f32x4*)x)[idx];
    u16x4 o;
    o[0] = f2bf(v[0]); o[1] = f2bf(v[1]); o[2] = f2bf(v[2]); o[3] = f2bf(v[3]);
    ((u16x4*)Xb)[idx] = o;
  }

  // T transpose: 64(k) x 64(c) tile per block; grid 256 = 8 k-tiles * 32 c-tiles
  const int k0 = (bid & 7) * 64, c0 = (bid >> 3) * 64;
#pragma unroll
  for (int i = 0; i < 4; ++i) {
    int row = i * 16 + (tid >> 4);          // k within tile
    int c4  = (tid & 15) * 4;               // col within tile
    f32x4 v = *(const f32x4*)(T + (size_t)(k0 + row) * NC + c0 + c4);
    tile[row][c4 + 0] = f2bf(v[0]);
    tile[row][c4 + 1] = f2bf(v[1]);
    tile[row][c4 + 2] = f2bf(v[2]);
    tile[row][c4 + 3] = f2bf(v[3]);
  }
  __syncthreads();
  const int c = tid >> 2, kq = (tid & 3) * 16;
  u16x8 w0, w1;
#pragma unroll
  for (int i = 0; i < 8; ++i) w0[i] = tile[kq + i][c];
#pragma unroll
  for (int i = 0; i < 8; ++i) w1[i] = tile[kq + 8 + i][c];
  unsigned short* dst = Wt + (size_t)(c0 + c) * NK + k0 + kq;
  *(u16x8*)dst = w0;
  *(u16x8*)(dst + 8) = w1;
}

// ---------------------------------------------------------------------------
// Kernel 2: mt[o][a][kd] = sum_k Xb[a][k] * Wt[c][k],  c = o*16+kd
// BM=32 (a), BN=64 (c), BK=128; grid (32 N) x (8 M) = 256 blocks, 4 waves.
// XOR-swizzled LDS (T2), reg-staged with issue-early/write-late (T14),
// 2-phase double buffer (T3-minimum).
// ---------------------------------------------------------------------------
__global__ __launch_bounds__(256) void k_gemm(const unsigned short* __restrict__ Xb,
                                              const unsigned short* __restrict__ Wt,
                                              float* __restrict__ mt) {
  constexpr int BK = 128;
  __shared__ unsigned short lds[2][12288];  // As[32*128] @0, Bs[64*128] @4096 (elems)
  const int tid = threadIdx.x;
  const int bn = blockIdx.x * 64;           // col base
  const int bm = blockIdx.y * 32;           // row base
  const int lane = tid & 63, wid = tid >> 6;
  const int wr = wid >> 1, wc = wid & 1;    // wave -> 16 rows x 32 cols

  // staging coords: A = 32 rows * 16 kgroups = 512 vec8 (2/thread);
  //                 B = 64 cols * 16 kgroups = 1024 vec8 (4/thread)
  int arow[2], akg[2], bcol[4], bkg[4];
#pragma unroll
  for (int r = 0; r < 2; ++r) { int idx = tid + r * 256; arow[r] = idx >> 4; akg[r] = idx & 15; }
#pragma unroll
  for (int r = 0; r < 4; ++r) { int idx = tid + r * 256; bcol[r] = idx >> 4; bkg[r] = idx & 15; }

  bf16x8 ra[2], rb[4];
  auto loadG = [&](int t) {
#pragma unroll
    for (int r = 0; r < 2; ++r)
      ra[r] = *(const bf16x8*)(Xb + (size_t)(bm + arow[r]) * NK + t * BK + akg[r] * 8);
#pragma unroll
    for (int r = 0; r < 4; ++r)
      rb[r] = *(const bf16x8*)(Wt + (size_t)(bn + bcol[r]) * NK + t * BK + bkg[r] * 8);
  };
  auto writeS = [&](int b) {
#pragma unroll
    for (int r = 0; r < 2; ++r)
      *(bf16x8*)(&lds[b][arow[r] * 128 + ((akg[r] ^ (arow[r] & 7)) << 3)]) = ra[r];
#pragma unroll
    for (int r = 0; r < 4; ++r)
      *(bf16x8*)(&lds[b][4096 + bcol[r] * 128 + ((bkg[r] ^ (bcol[r] & 7)) << 3)]) = rb[r];
  };

  f32x4 acc[2] = {};
  const int rowA  = wr * 16 + (lane & 15);
  const int colB0 = wc * 32 + (lane & 15);

  loadG(0); writeS(0); __syncthreads();
#pragma unroll
  for (int t = 0; t < 4; ++t) {
    if (t < 3) loadG(t + 1);                // issue next-tile loads early
    const int b = t & 1;
#pragma unroll
    for (int ks = 0; ks < 4; ++ks) {
      int kg = ks * 4 + (lane >> 4);        // k-group of 8: k = ks*32 + (lane>>4)*8
      bf16x8 af = *(const bf16x8*)(&lds[b][rowA * 128 + ((kg ^ (rowA & 7)) << 3)]);
#pragma unroll
      for (int ct = 0; ct < 2; ++ct) {
        int col = colB0 + ct * 16;
        bf16x8 bv = *(const bf16x8*)(&lds[b][4096 + col * 128 + ((kg ^ (col & 7)) << 3)]);
        acc[ct] = __builtin_amdgcn_mfma_f32_16x16x32_bf16(af, bv, acc[ct], 0, 0, 0);
      }
    }
    if (t < 3) writeS((t + 1) & 1);         // write-late: vmcnt drains under MFMA
    __syncthreads();
  }

  // C/D layout (m89-verified): col = lane&15, row = (lane>>4)*4 + j
#pragma unroll
  for (int ct = 0; ct < 2; ++ct) {
    int colg = bn + wc * 32 + ct * 16 + (lane & 15);
    int o = colg >> 4, kd = colg & 15;      // 16-col tile == exactly one o
    int rbase = bm + wr * 16 + (lane >> 4) * 4;
#pragma unroll
    for (int j = 0; j < 4; ++j)
      mt[(size_t)o * 4096 + (size_t)(rbase + j) * 16 + kd] = acc[ct][j];
  }
}

// ---------------------------------------------------------------------------
// Kernel 3: o_b[b][o] = sum_a exp(-sum_kd |mt[o][a][kd] - mt[o][b][kd]|)
// grid 256 = (o, b-half); 256 thr = 64 b-groups (2 rows each) x 4-way a-split.
// a-rows streamed via wave-uniform loads (aq constant per wave). x-copy folded.
// ---------------------------------------------------------------------------
__global__ __launch_bounds__(256) void k_pair(const float* __restrict__ mt,
                                              const float* __restrict__ x,
                                              float* __restrict__ out) {
  __shared__ float red[4][128];
  const int tid = threadIdx.x, bid = blockIdx.x;
  const int o = bid >> 1, bh = bid & 1;
  const int bg = tid & 63, aq = tid >> 6;   // aq uniform within each wave
  const float* __restrict__ mo = mt + (size_t)o * 4096;

  const int r0 = bh * 128 + bg * 2;
  f32x4 b0[4], b1[4];
#pragma unroll
  for (int i = 0; i < 4; ++i) {
    b0[i] = *(const f32x4*)(mo + r0 * 16 + i * 4);
    b1[i] = *(const f32x4*)(mo + (r0 + 1) * 16 + i * 4);
  }

  float acc0 = 0.f, acc1 = 0.f;
  const int a0 = aq * 64;
#pragma unroll 4
  for (int a = a0; a < a0 + 64; ++a) {
    const float* ar = mo + a * 16;          // wave-uniform address
    float n0 = 0.f, n1 = 0.f;
#pragma unroll
    for (int i = 0; i < 4; ++i) {
      f32x4 ra = *(const f32x4*)(ar + i * 4);
#pragma unroll
      for (int j = 0; j < 4; ++j) {
        n0 += fabsf(ra[j] - b0[i][j]);      // sub + add|abs| (VOP3 modifier)
        n1 += fabsf(ra[j] - b1[i][j]);
      }
    }
    acc0 += __expf(-n0);                    // underflows to 0 for a!=b; exp(0)=1 self
    acc1 += __expf(-n1);
  }
  red[aq][bg * 2]     = acc0;
  red[aq][bg * 2 + 1] = acc1;
  __syncthreads();
  if (tid < 128) {
    float s = red[0][tid] + red[1][tid] + red[2][tid] + red[3][tid];
    out[(size_t)(bh * 128 + tid) * OUTW + NK + o] = s;
    // x-copy: 32768 float4 total = 256 blocks * 128
    int idx = bid * 128 + tid;
    int row = idx >> 7, c4 = (idx & 127) * 4;
    *(f32x4*)(out + (size_t)row * OUTW + c4) = *(const f32x4*)(x + (size_t)row * NK + c4);
  }
}

// ---------------------------------------------------------------------------
extern "C" void kernel_launch(void* const* d_in, const int* in_sizes, int n_in,
                              void* d_out, int out_size, void* d_ws, size_t ws_size,
                              hipStream_t stream) {
  const float* x = (const float*)d_in[0];
  const float* T = (const float*)d_in[1];
  float* out = (float*)d_out;
  char* ws = (char*)d_ws;
  float* mt = (float*)ws;                                           // 2 MB
  unsigned short* Xb = (unsigned short*)(ws + (2u << 20));          // 256 KB
  unsigned short* Wt = (unsigned short*)(ws + (2u << 20) + (256u << 10)); // 2 MB

  k_prep<<<256, 256, 0, stream>>>(x, T, Xb, Wt);
  k_gemm<<<dim3(32, 8), 256, 0, stream>>>(Xb, Wt, mt);
  k_pair<<<256, 256, 0, stream>>>(mt, x, out);
}

// Round 2
// 30.615 us; speedup vs baseline: 1.2485x; 1.2485x over previous
//
#include <hip/hip_runtime.h>
#include <stdint.h>

#define NB 256       // batch
#define NK 512       // in_features
#define NO 128       // out_features
#define NKD 16       // kernel_dims
#define NC 2048      // NO*NKD
#define OUTW 640     // NK + NO

typedef __attribute__((ext_vector_type(8))) short bf16x8;   // 8 bf16 bit patterns (4 VGPRs)
typedef __attribute__((ext_vector_type(4))) float f32x4;
typedef __attribute__((ext_vector_type(8))) unsigned short u16x8;
typedef __attribute__((ext_vector_type(4))) unsigned short u16x4;

__device__ __forceinline__ unsigned short f2bf(float f) {
  uint32_t u = __builtin_bit_cast(uint32_t, f);
  u += 0x7fffu + ((u >> 16) & 1u);          // RTNE (inputs are finite normals)
  return (unsigned short)(u >> 16);
}

// ---------------------------------------------------------------------------
// Kernel 1: x -> bf16 (Xb[256][512]); T[512][2048] -> transposed bf16 Wt[2048][512]
// ---------------------------------------------------------------------------
__global__ __launch_bounds__(256) void k_prep(const float* __restrict__ x,
                                              const float* __restrict__ T,
                                              unsigned short* __restrict__ Xb,
                                              unsigned short* __restrict__ Wt) {
  __shared__ unsigned short tile[64][66];   // +2 pad breaks bank collisions
  const int tid = threadIdx.x, bid = blockIdx.x;

  // x convert: 32768 float4 total = 256 blocks * 128
  if (tid < 128) {
    int idx = bid * 128 + tid;
    f32x4 v = ((const f32x4*)x)[idx];
    u16x4 o;
    o[0] = f2bf(v[0]); o[1] = f2bf(v[1]); o[2] = f2bf(v[2]); o[3] = f2bf(v[3]);
    ((u16x4*)Xb)[idx] = o;
  }

  // T transpose: 64(k) x 64(c) tile per block; grid 256 = 8 k-tiles * 32 c-tiles
  const int k0 = (bid & 7) * 64, c0 = (bid >> 3) * 64;
#pragma unroll
  for (int i = 0; i < 4; ++i) {
    int row = i * 16 + (tid >> 4);          // k within tile
    int c4  = (tid & 15) * 4;               // col within tile
    f32x4 v = *(const f32x4*)(T + (size_t)(k0 + row) * NC + c0 + c4);
    tile[row][c4 + 0] = f2bf(v[0]);
    tile[row][c4 + 1] = f2bf(v[1]);
    tile[row][c4 + 2] = f2bf(v[2]);
    tile[row][c4 + 3] = f2bf(v[3]);
  }
  __syncthreads();
  const int c = tid >> 2, kq = (tid & 3) * 16;
  u16x8 w0, w1;
#pragma unroll
  for (int i = 0; i < 8; ++i) w0[i] = tile[kq + i][c];
#pragma unroll
  for (int i = 0; i < 8; ++i) w1[i] = tile[kq + 8 + i][c];
  unsigned short* dst = Wt + (size_t)(c0 + c) * NK + k0 + kq;
  *(u16x8*)dst = w0;
  *(u16x8*)(dst + 8) = w1;
}

// ---------------------------------------------------------------------------
// Kernel 2: mt[o][a][kd] = sum_k Xb[a][k] * Wt[c][k],  c = o*16+kd
// BM=32 (a), BN=64 (c), BK=128; grid (32 N) x (8 M) = 256 blocks, 4 waves.
// XOR-swizzled LDS (T2), reg-staged with issue-early/write-late (T14),
// 2-phase double buffer.
// ---------------------------------------------------------------------------
__global__ __launch_bounds__(256) void k_gemm(const unsigned short* __restrict__ Xb,
                                              const unsigned short* __restrict__ Wt,
                                              float* __restrict__ mt) {
  constexpr int BK = 128;
  __shared__ unsigned short lds[2][12288];  // As[32*128] @0, Bs[64*128] @4096 (elems)
  const int tid = threadIdx.x;
  const int bn = blockIdx.x * 64;           // col base
  const int bm = blockIdx.y * 32;           // row base
  const int lane = tid & 63, wid = tid >> 6;
  const int wr = wid >> 1, wc = wid & 1;    // wave -> 16 rows x 32 cols

  int arow[2], akg[2], bcol[4], bkg[4];
#pragma unroll
  for (int r = 0; r < 2; ++r) { int idx = tid + r * 256; arow[r] = idx >> 4; akg[r] = idx & 15; }
#pragma unroll
  for (int r = 0; r < 4; ++r) { int idx = tid + r * 256; bcol[r] = idx >> 4; bkg[r] = idx & 15; }

  bf16x8 ra[2], rb[4];
  auto loadG = [&](int t) {
#pragma unroll
    for (int r = 0; r < 2; ++r)
      ra[r] = *(const bf16x8*)(Xb + (size_t)(bm + arow[r]) * NK + t * BK + akg[r] * 8);
#pragma unroll
    for (int r = 0; r < 4; ++r)
      rb[r] = *(const bf16x8*)(Wt + (size_t)(bn + bcol[r]) * NK + t * BK + bkg[r] * 8);
  };
  auto writeS = [&](int b) {
#pragma unroll
    for (int r = 0; r < 2; ++r)
      *(bf16x8*)(&lds[b][arow[r] * 128 + ((akg[r] ^ (arow[r] & 7)) << 3)]) = ra[r];
#pragma unroll
    for (int r = 0; r < 4; ++r)
      *(bf16x8*)(&lds[b][4096 + bcol[r] * 128 + ((bkg[r] ^ (bcol[r] & 7)) << 3)]) = rb[r];
  };

  f32x4 acc[2] = {};
  const int rowA  = wr * 16 + (lane & 15);
  const int colB0 = wc * 32 + (lane & 15);

  loadG(0); writeS(0); __syncthreads();
#pragma unroll
  for (int t = 0; t < 4; ++t) {
    if (t < 3) loadG(t + 1);                // issue next-tile loads early
    const int b = t & 1;
#pragma unroll
    for (int ks = 0; ks < 4; ++ks) {
      int kg = ks * 4 + (lane >> 4);        // k-group of 8: k = ks*32 + (lane>>4)*8
      bf16x8 af = *(const bf16x8*)(&lds[b][rowA * 128 + ((kg ^ (rowA & 7)) << 3)]);
#pragma unroll
      for (int ct = 0; ct < 2; ++ct) {
        int col = colB0 + ct * 16;
        bf16x8 bv = *(const bf16x8*)(&lds[b][4096 + col * 128 + ((kg ^ (col & 7)) << 3)]);
        acc[ct] = __builtin_amdgcn_mfma_f32_16x16x32_bf16(af, bv, acc[ct], 0, 0, 0);
      }
    }
    if (t < 3) writeS((t + 1) & 1);         // write-late: vmcnt drains under MFMA
    __syncthreads();
  }

  // C/D layout (m89-verified): col = lane&15, row = (lane>>4)*4 + j
#pragma unroll
  for (int ct = 0; ct < 2; ++ct) {
    int colg = bn + wc * 32 + ct * 16 + (lane & 15);
    int o = colg >> 4, kd = colg & 15;      // 16-col tile == exactly one o
    int rbase = bm + wr * 16 + (lane >> 4) * 4;
#pragma unroll
    for (int j = 0; j < 4; ++j)
      mt[(size_t)o * 4096 + (size_t)(rbase + j) * 16 + kd] = acc[ct][j];
  }
}

// ---------------------------------------------------------------------------
// Kernel 3: o_b[b][o] = sum_a exp(-sum_kd |mt[o][a][kd] - mt[o][b][kd]|)
// grid 512 = (o, b-quarter); 256 thr = 16 bg (4 b-rows each, in regs) x 16 aq.
// R=4 b-rows/thread amortizes each a-row fetch over 280 cyc of VALU.
// All data straight from L1 (16KB o-slice resident); LDS only for reduction.
// ---------------------------------------------------------------------------
__global__ __launch_bounds__(256) void k_pair(const float* __restrict__ mt,
                                              const float* __restrict__ x,
                                              float* __restrict__ out) {
  __shared__ float red[16][64];             // [aq][b-row-in-block]
  const int tid = threadIdx.x, bid = blockIdx.x;
  const int o = bid >> 2, bq = bid & 3;
  const int bg = tid & 15, aq = tid >> 4;
  const float* __restrict__ mo = mt + (size_t)o * 4096;

  const int r0 = bq * 64 + bg * 4;          // this thread's 4 b-rows
  f32x4 br[4][4];
#pragma unroll
  for (int r = 0; r < 4; ++r)
#pragma unroll
    for (int i = 0; i < 4; ++i)
      br[r][i] = *(const f32x4*)(mo + (size_t)(r0 + r) * 16 + i * 4);

  float acc[4] = {0.f, 0.f, 0.f, 0.f};
#pragma unroll 2
  for (int it = 0; it < 16; ++it) {
    const int a = aq * 16 + it;
    f32x4 ra[4];
#pragma unroll
    for (int i = 0; i < 4; ++i)
      ra[i] = *(const f32x4*)(mo + (size_t)a * 16 + i * 4);
#pragma unroll
    for (int r = 0; r < 4; ++r) {
      float n = 0.f;
#pragma unroll
      for (int i = 0; i < 4; ++i)
#pragma unroll
        for (int j = 0; j < 4; ++j)
          n += fabsf(ra[i][j] - br[r][i][j]);   // sub + add|abs| (VOP3 modifier)
      acc[r] += __expf(-n);                     // 0 for a!=b (underflow), 1 self
    }
  }
#pragma unroll
  for (int r = 0; r < 4; ++r) red[aq][bg * 4 + r] = acc[r];
  __syncthreads();
  if (tid < 64) {
    float s = 0.f;
#pragma unroll
    for (int q = 0; q < 16; ++q) s += red[q][tid];
    out[(size_t)(bq * 64 + tid) * OUTW + NK + o] = s;
    // x-copy: 512 blocks * 64 f32x4 = 32768 total
    int idx = bid * 64 + tid;
    int row = idx >> 7, c4 = (idx & 127) * 4;
    *(f32x4*)(out + (size_t)row * OUTW + c4) = *(const f32x4*)(x + (size_t)row * NK + c4);
  }
}

// ---------------------------------------------------------------------------
extern "C" void kernel_launch(void* const* d_in, const int* in_sizes, int n_in,
                              void* d_out, int out_size, void* d_ws, size_t ws_size,
                              hipStream_t stream) {
  const float* x = (const float*)d_in[0];
  const float* T = (const float*)d_in[1];
  float* out = (float*)d_out;
  char* ws = (char*)d_ws;
  float* mt = (float*)ws;                                           // 2 MB
  unsigned short* Xb = (unsigned short*)(ws + (2u << 20));          // 256 KB
  unsigned short* Wt = (unsigned short*)(ws + (2u << 20) + (256u << 10)); // 2 MB

  k_prep<<<256, 256, 0, stream>>>(x, T, Xb, Wt);
  k_gemm<<<dim3(32, 8), 256, 0, stream>>>(Xb, Wt, mt);
  k_pair<<<512, 256, 0, stream>>>(mt, x, out);
}

// Round 3
// 29.532 us; speedup vs baseline: 1.2943x; 1.0367x over previous
//
#include <hip/hip_runtime.h>
#include <stdint.h>

#define NB 256       // batch
#define NK 512       // in_features
#define NO 128       // out_features
#define NKD 16       // kernel_dims
#define NC 2048      // NO*NKD
#define OUTW 640     // NK + NO

typedef __attribute__((ext_vector_type(8))) short bf16x8;   // 8 bf16 (4 VGPRs)
typedef __attribute__((ext_vector_type(4))) float f32x4;
typedef __attribute__((ext_vector_type(8))) unsigned short u16x8;

__device__ __forceinline__ unsigned short f2bf(float f) {
  uint32_t u = __builtin_bit_cast(uint32_t, f);
  u += 0x7fffu + ((u >> 16) & 1u);          // RTNE (inputs are finite normals)
  return (unsigned short)(u >> 16);
}

// ---------------------------------------------------------------------------
// Kernel 1 (fused prep+gemm): mt[o][a][kd] = sum_k x[a][k] * T[k][o*16+kd]
// BM=32 (a), BN=64 (c), BK=128, K=512 in 4 chunks; grid (32 N) x (8 M).
// A staged from f32 x (cvt in regs); B staged from f32 T with in-LDS
// transpose via scalar ds_write_u16 into the XOR-swizzled [col][k] layout
// that the (round-1-verified) fragment reads expect. Double-buffered,
// issue-early/write-late (T14). x-copy to out folded in (independent work).
// ---------------------------------------------------------------------------
__global__ __launch_bounds__(256) void k_gemm(const float* __restrict__ x,
                                              const float* __restrict__ T,
                                              const float* __restrict__ xc,
                                              float* __restrict__ out,
                                              float* __restrict__ mt) {
  __shared__ unsigned short lds[2][12288];  // As[32*128] @0, Bs[64*128] @4096 (elems)
  const int tid = threadIdx.x;
  const int bn = blockIdx.x * 64;           // col base (c)
  const int bm = blockIdx.y * 32;           // row base (a)
  const int lane = tid & 63, wid = tid >> 6;
  const int wr = wid >> 1, wc = wid & 1;    // wave -> 16 rows x 32 cols

  // x-copy: 256 blocks * 128 f32x4 = 32768 (independent of GEMM)
  {
    const int bid = blockIdx.y * 32 + blockIdx.x;
    if (tid < 128) {
      int idx = bid * 128 + tid;
      int row = idx >> 7, c4 = (idx & 127) * 4;
      *(f32x4*)(out + (size_t)row * OUTW + c4) = *(const f32x4*)(xc + (size_t)row * NK + c4);
    }
  }

  // A staging coords: 32 rows x 16 kgroups(8) = 512 slots, 2/thread
  int arow[2], akg[2];
#pragma unroll
  for (int s = 0; s < 2; ++s) { int idx = tid + s * 256; arow[s] = idx >> 4; akg[s] = idx & 15; }
  // B staging coords: 128 k x 16 c-quads = 2048 slots, 8/thread
  int bk[8], bc4[8];
#pragma unroll
  for (int s = 0; s < 8; ++s) { int idx = tid + s * 256; bk[s] = idx >> 4; bc4[s] = (idx & 15) * 4; }

  f32x4 raf[2][2], rbf[8];
  auto loadG = [&](int t) {
#pragma unroll
    for (int s = 0; s < 2; ++s) {
      const float* p = x + (size_t)(bm + arow[s]) * NK + t * 128 + akg[s] * 8;
      raf[s][0] = *(const f32x4*)p;
      raf[s][1] = *(const f32x4*)(p + 4);
    }
#pragma unroll
    for (int s = 0; s < 8; ++s)
      rbf[s] = *(const f32x4*)(T + (size_t)(t * 128 + bk[s]) * NC + bn + bc4[s]);
  };
  auto writeS = [&](int b) {
#pragma unroll
    for (int s = 0; s < 2; ++s) {
      u16x8 w;
#pragma unroll
      for (int j = 0; j < 4; ++j) { w[j] = f2bf(raf[s][0][j]); w[4 + j] = f2bf(raf[s][1][j]); }
      *(u16x8*)(&lds[b][arow[s] * 128 + ((akg[s] ^ (arow[s] & 7)) << 3)]) = w;
    }
#pragma unroll
    for (int s = 0; s < 8; ++s) {
      const int k = bk[s], klo = k & 7, kg = k >> 3;
#pragma unroll
      for (int j = 0; j < 4; ++j) {
        int c = bc4[s] + j;
        lds[b][4096 + c * 128 + ((kg ^ (c & 7)) << 3) + klo] = f2bf(rbf[s][j]);
      }
    }
  };

  f32x4 acc[2] = {};
  const int rowA  = wr * 16 + (lane & 15);
  const int colB0 = wc * 32 + (lane & 15);

  loadG(0); writeS(0); __syncthreads();
#pragma unroll
  for (int t = 0; t < 4; ++t) {
    if (t < 3) loadG(t + 1);                // issue next-chunk loads early
    const int b = t & 1;
#pragma unroll
    for (int ks = 0; ks < 4; ++ks) {
      int kg = ks * 4 + (lane >> 4);        // k-group of 8
      bf16x8 af = *(const bf16x8*)(&lds[b][rowA * 128 + ((kg ^ (rowA & 7)) << 3)]);
#pragma unroll
      for (int ct = 0; ct < 2; ++ct) {
        int col = colB0 + ct * 16;
        bf16x8 bv = *(const bf16x8*)(&lds[b][4096 + col * 128 + ((kg ^ (col & 7)) << 3)]);
        acc[ct] = __builtin_amdgcn_mfma_f32_16x16x32_bf16(af, bv, acc[ct], 0, 0, 0);
      }
    }
    if (t < 3) writeS((t + 1) & 1);         // cvt+write under MFMA shadow
    __syncthreads();
  }

  // C/D layout (verified): col = lane&15, row = (lane>>4)*4 + j
#pragma unroll
  for (int ct = 0; ct < 2; ++ct) {
    int colg = bn + wc * 32 + ct * 16 + (lane & 15);
    int o = colg >> 4, kd = colg & 15;
    int rbase = bm + wr * 16 + (lane >> 4) * 4;
#pragma unroll
    for (int j = 0; j < 4; ++j)
      mt[(size_t)o * 4096 + (size_t)(rbase + j) * 16 + kd] = acc[ct][j];
  }
}

// ---------------------------------------------------------------------------
// Kernel 2: o_b[b][o] = sum_a exp(-sum_kd |mt[o][a][kd] - mt[o][b][kd]|)
// grid 1024 = (o, b-eighth) -> 4 blocks/CU = 4 waves/SIMD (latency hiding).
// 256 thr = 8 bg (4 b-rows each, in regs) x 32 aq (8 a's each).
// a-row addresses uniform per 8 lanes -> L1 broadcast; LDS only for reduce.
// ---------------------------------------------------------------------------
__global__ __launch_bounds__(256) void k_pair(const float* __restrict__ mt,
                                              float* __restrict__ out) {
  __shared__ float red[32][32];             // [aq][b-row-in-block]
  const int tid = threadIdx.x, bid = blockIdx.x;
  const int o = bid >> 3, bq = bid & 7;
  const int bg = tid & 7, aq = tid >> 3;
  const float* __restrict__ mo = mt + (size_t)o * 4096;

  const int r0 = bq * 32 + bg * 4;          // this thread's 4 b-rows
  f32x4 br[4][4];
#pragma unroll
  for (int r = 0; r < 4; ++r)
#pragma unroll
    for (int i = 0; i < 4; ++i)
      br[r][i] = *(const f32x4*)(mo + (size_t)(r0 + r) * 16 + i * 4);

  float acc[4] = {0.f, 0.f, 0.f, 0.f};
#pragma unroll 2
  for (int it = 0; it < 8; ++it) {
    const int a = aq * 8 + it;
    f32x4 ra[4];
#pragma unroll
    for (int i = 0; i < 4; ++i)
      ra[i] = *(const f32x4*)(mo + (size_t)a * 16 + i * 4);
#pragma unroll
    for (int r = 0; r < 4; ++r) {
      float n = 0.f;
#pragma unroll
      for (int i = 0; i < 4; ++i)
#pragma unroll
        for (int j = 0; j < 4; ++j)
          n += fabsf(ra[i][j] - br[r][i][j]);   // sub + add|abs|
      acc[r] += __expf(-n);                     // 0 for a!=b (underflow), 1 self
    }
  }
#pragma unroll
  for (int r = 0; r < 4; ++r) red[aq][bg * 4 + r] = acc[r];
  __syncthreads();
  if (tid < 32) {
    float s = 0.f;
#pragma unroll
    for (int q = 0; q < 32; ++q) s += red[q][tid];
    out[(size_t)(bq * 32 + tid) * OUTW + NK + o] = s;
  }
}

// ---------------------------------------------------------------------------
extern "C" void kernel_launch(void* const* d_in, const int* in_sizes, int n_in,
                              void* d_out, int out_size, void* d_ws, size_t ws_size,
                              hipStream_t stream) {
  const float* x = (const float*)d_in[0];
  const float* T = (const float*)d_in[1];
  float* out = (float*)d_out;
  float* mt = (float*)d_ws;                 // 2 MB scratch

  k_gemm<<<dim3(32, 8), 256, 0, stream>>>(x, T, x, out, mt);
  k_pair<<<1024, 256, 0, stream>>>(mt, out);
}

// Round 4
// 21.764 us; speedup vs baseline: 1.7562x; 1.3569x over previous
//
#include <hip/hip_runtime.h>
#include <stdint.h>

#define NB 256       // batch
#define NK 512       // in_features
#define NO 128       // out_features
#define NKD 16       // kernel_dims
#define NC 2048      // NO*NKD
#define OUTW 640     // NK + NO

typedef __attribute__((ext_vector_type(8))) short bf16x8;   // 8 bf16 (4 VGPRs)
typedef __attribute__((ext_vector_type(4))) float f32x4;
typedef __attribute__((ext_vector_type(4))) unsigned int u32x4;
typedef __attribute__((ext_vector_type(2))) unsigned int u32x2;

// pack 2 f32 -> 2 bf16 (truncation) in ONE v_perm_b32
__device__ __forceinline__ unsigned int pk(float lo, float hi) {
  return __builtin_amdgcn_perm(__builtin_bit_cast(unsigned int, hi),
                               __builtin_bit_cast(unsigned int, lo), 0x07060302u);
}

// ---------------------------------------------------------------------------
// Kernel 1 (fused prep+gemm): mt[o][a][kd] = sum_k x[a][k] * T[k][o*16+kd]
// BM=32 (a), BN=64 (c), BK=128, K=512 in 4 chunks; grid (32 N) x (8 M).
// A: f32 loads -> v_perm bf16 pack -> vectorized swizzled LDS writes.
// B: 4k x 4c micro-tile/thread -> in-register transpose via v_perm ->
//    ds_write_b64 into the (round-1-verified) XOR-swizzled [c][k] layout.
// Double-buffered, issue-early/write-late. x-copy folded in.
// ---------------------------------------------------------------------------
__global__ __launch_bounds__(256) void k_gemm(const float* __restrict__ x,
                                              const float* __restrict__ T,
                                              float* __restrict__ out,
                                              float* __restrict__ mt) {
  __shared__ unsigned short lds[2][12288];  // As[32*128] @0, Bs[64*128] @4096 (elems)
  const int tid = threadIdx.x;
  const int bn = blockIdx.x * 64;           // col base (c)
  const int bm = blockIdx.y * 32;           // row base (a)
  const int lane = tid & 63, wid = tid >> 6;
  const int wr = wid >> 1, wc = wid & 1;    // wave -> 16 rows x 32 cols

  // x-copy to out (independent work): 256 blocks * 128 f32x4
  {
    const int bid = blockIdx.y * 32 + blockIdx.x;
    if (tid < 128) {
      int idx = bid * 128 + tid;
      int row = idx >> 7, c4 = (idx & 127) * 4;
      *(f32x4*)(out + (size_t)row * OUTW + c4) = *(const f32x4*)(x + (size_t)row * NK + c4);
    }
  }

  // A staging: 32 rows x 16 kgroups(8) = 512 slots, 2/thread
  int arow[2], akg[2];
#pragma unroll
  for (int s = 0; s < 2; ++s) { int idx = tid + s * 256; arow[s] = idx >> 4; akg[s] = idx & 15; }
  // B staging: 32 kblk(4) x 16 cblk(4) = 512 micro-tiles, 2/thread
  int bkb[2], bcb[2];
#pragma unroll
  for (int s = 0; s < 2; ++s) { int idx = tid + s * 256; bkb[s] = idx >> 4; bcb[s] = idx & 15; }

  f32x4 raf[2][2], rbf[2][4];
  auto loadG = [&](int t) {
#pragma unroll
    for (int s = 0; s < 2; ++s) {
      const float* p = x + (size_t)(bm + arow[s]) * NK + t * 128 + akg[s] * 8;
      raf[s][0] = *(const f32x4*)p;
      raf[s][1] = *(const f32x4*)(p + 4);
    }
#pragma unroll
    for (int s = 0; s < 2; ++s)
#pragma unroll
      for (int j = 0; j < 4; ++j)
        rbf[s][j] = *(const f32x4*)(T + (size_t)(t * 128 + bkb[s] * 4 + j) * NC + bn + bcb[s] * 4);
  };
  auto writeS = [&](int b) {
#pragma unroll
    for (int s = 0; s < 2; ++s) {           // A: k-contiguous pack, b128 write
      u32x4 w;
      w[0] = pk(raf[s][0][0], raf[s][0][1]);
      w[1] = pk(raf[s][0][2], raf[s][0][3]);
      w[2] = pk(raf[s][1][0], raf[s][1][1]);
      w[3] = pk(raf[s][1][2], raf[s][1][3]);
      *(u32x4*)(&lds[b][arow[s] * 128 + ((akg[s] ^ (arow[s] & 7)) << 3)]) = w;
    }
#pragma unroll
    for (int s = 0; s < 2; ++s) {           // B: in-reg transpose, b64 writes
      const int kb = bkb[s], kg = kb >> 1, k0l = (kb & 1) * 4;
#pragma unroll
      for (int c = 0; c < 4; ++c) {
        u32x2 w;
        w[0] = pk(rbf[s][0][c], rbf[s][1][c]);
        w[1] = pk(rbf[s][2][c], rbf[s][3][c]);
        int bc = bcb[s] * 4 + c;
        *(u32x2*)(&lds[b][4096 + bc * 128 + ((kg ^ (bc & 7)) << 3) + k0l]) = w;
      }
    }
  };

  f32x4 acc[2] = {};
  const int rowA  = wr * 16 + (lane & 15);
  const int colB0 = wc * 32 + (lane & 15);

  loadG(0); writeS(0); __syncthreads();
#pragma unroll
  for (int t = 0; t < 4; ++t) {
    if (t < 3) loadG(t + 1);                // issue next-chunk loads early
    const int b = t & 1;
#pragma unroll
    for (int ks = 0; ks < 4; ++ks) {
      int kg = ks * 4 + (lane >> 4);        // k-group of 8
      bf16x8 af = *(const bf16x8*)(&lds[b][rowA * 128 + ((kg ^ (rowA & 7)) << 3)]);
#pragma unroll
      for (int ct = 0; ct < 2; ++ct) {
        int col = colB0 + ct * 16;
        bf16x8 bv = *(const bf16x8*)(&lds[b][4096 + col * 128 + ((kg ^ (col & 7)) << 3)]);
        acc[ct] = __builtin_amdgcn_mfma_f32_16x16x32_bf16(af, bv, acc[ct], 0, 0, 0);
      }
    }
    if (t < 3) writeS((t + 1) & 1);         // pack+write under MFMA/load shadow
    __syncthreads();
  }

  // C/D layout (verified): col = lane&15, row = (lane>>4)*4 + j
#pragma unroll
  for (int ct = 0; ct < 2; ++ct) {
    int colg = bn + wc * 32 + ct * 16 + (lane & 15);
    int o = colg >> 4, kd = colg & 15;
    int rbase = bm + wr * 16 + (lane >> 4) * 4;
#pragma unroll
    for (int j = 0; j < 4; ++j)
      mt[(size_t)o * 4096 + (size_t)(rbase + j) * 16 + kd] = acc[ct][j];
  }
}

// ---------------------------------------------------------------------------
// Kernel 2: o_b[b][o] = sum_a exp(-sum_kd |mt[o][a][kd] - mt[o][b][kd]|)
// grid 1024 = (o, b-eighth), 4 blocks/CU. The 16 KB o-slice is staged in LDS
// (stride-20-float rows: 16B-aligned, and with a = it*32 + wave*8 + aqr the
// 8 lane-group reads hit disjoint 4-word bank spans -> conflict-free b128
// broadcast). Inner loop never touches L1/L2.
// ---------------------------------------------------------------------------
__global__ __launch_bounds__(256, 4) void k_pair(const float* __restrict__ mt,
                                                 float* __restrict__ out) {
  __shared__ float S[256 * 20];             // a-row r at S[r*20], 16 floats used
  __shared__ float red[32][33];             // [aq][b-row], padded
  const int tid = threadIdx.x, bid = blockIdx.x;
  const int o = bid >> 3, bq = bid & 7;
  const float* __restrict__ mo = mt + (size_t)o * 4096;

  // stage o-slice: 1024 f32x4, coalesced
#pragma unroll
  for (int s = 0; s < 4; ++s) {
    int idx = tid + s * 256;
    f32x4 v = ((const f32x4*)mo)[idx];
    *(f32x4*)(&S[(idx >> 2) * 20 + (idx & 3) * 4]) = v;
  }
  __syncthreads();

  const int bg = tid & 7, aq = tid >> 3;    // aq 0..31
  const int wv = tid >> 6, aqr = aq & 7;    // wv = wave index (uniform/wave)
  const int r0 = bq * 32 + bg * 4;          // this thread's 4 b-rows

  f32x4 br[4][4];
#pragma unroll
  for (int r = 0; r < 4; ++r)
#pragma unroll
    for (int i = 0; i < 4; ++i)
      br[r][i] = *(const f32x4*)(&S[(r0 + r) * 20 + i * 4]);

  float acc[4] = {0.f, 0.f, 0.f, 0.f};
#pragma unroll 2
  for (int it = 0; it < 8; ++it) {
    const int a = it * 32 + wv * 8 + aqr;   // bank-disjoint across lane groups
    f32x4 ra[4];
#pragma unroll
    for (int i = 0; i < 4; ++i)
      ra[i] = *(const f32x4*)(&S[a * 20 + i * 4]);
#pragma unroll
    for (int r = 0; r < 4; ++r) {
      float n = 0.f;
#pragma unroll
      for (int i = 0; i < 4; ++i)
#pragma unroll
        for (int j = 0; j < 4; ++j)
          n += fabsf(ra[i][j] - br[r][i][j]);   // sub + add|abs|
      acc[r] += __expf(-n);                     // 0 for a!=b (underflow), 1 self
    }
  }
#pragma unroll
  for (int r = 0; r < 4; ++r) red[aq][bg * 4 + r] = acc[r];
  __syncthreads();
  if (tid < 32) {
    float s = 0.f;
#pragma unroll
    for (int q = 0; q < 32; ++q) s += red[q][tid];
    out[(size_t)(bq * 32 + tid) * OUTW + NK + o] = s;
  }
}

// ---------------------------------------------------------------------------
extern "C" void kernel_launch(void* const* d_in, const int* in_sizes, int n_in,
                              void* d_out, int out_size, void* d_ws, size_t ws_size,
                              hipStream_t stream) {
  const float* x = (const float*)d_in[0];
  const float* T = (const float*)d_in[1];
  float* out = (float*)d_out;
  float* mt = (float*)d_ws;                 // 2 MB scratch

  k_gemm<<<dim3(32, 8), 256, 0, stream>>>(x, T, out, mt);
  k_pair<<<1024, 256, 0, stream>>>(mt, out);
}